// Round 5
// baseline (331.905 us; speedup 1.0000x reference)
//
#include <hip/hip_runtime.h>

typedef unsigned int u32;

#define DIM 16384
#define NT  1024

// Swizzle v4 (R3/R4-verified).
__host__ __device__ constexpr u32 swzN(u32 d) {
    u32 b0 = ((d >> 4) ^ (d >> 5)) & 1u;
    u32 b1 = (d >> 4) & 1u;
    u32 b2 = ((d >> 7) ^ (d >> 8)) & 1u;
    u32 b3 = ((d >> 6) ^ (d >> 8)) & 1u;
    return d ^ b0 ^ (b1 << 1) ^ (b2 << 2) ^ (b3 << 3);
}

// CNOT-ring basis map (HW-validated).
__host__ __device__ constexpr u32 mmap(u32 y) {
    u32 s = y;
    s ^= s >> 1; s ^= s >> 2; s ^= s >> 4; s ^= s >> 8;
    return (s & 0x1FFFu) | (((s ^ (y >> 13)) & 1u) << 13);
}
__host__ __device__ constexpr u32 mpow(u32 x, int L) {
    for (int i = 0; i < L; ++i) x = mmap(x);
    return x;
}

// 7-pass schedule (R4-verified, proven minimal: 3+3+3-2).
constexpr u32 PV3[5] = {0x040, 0x080, 0x100, 0x200, 0x400};
constexpr u32 PV4[5] = {0x006, 0x00C, 0x018, 0x030, 0x060};
constexpr u32 PV5[5] = {0x3001, 0x0003, 0x0C00, 0x1800, 0x3000};
constexpr u32 PV6[5] = {0x005, 0x00A, 0x014, 0x028, 0x050};
constexpr u32 PV7[5] = {0x0A0, 0x140, 0x280, 0x500, 0xA00};

__host__ __device__ constexpr u32 moff(const u32* v, int r) {
    u32 m = 0;
    for (int i = 0; i < 5; ++i) if ((r >> i) & 1) m ^= v[i];
    return m;
}
__host__ __device__ constexpr u32 parmask(const u32* v, int L, int b) {
    u32 pm = 0;
    for (int r = 0; r < 32; ++r)
        pm |= ((mpow(moff(v, r), L) >> b) & 1u) << r;
    return pm;
}
__host__ __device__ constexpr int hbit(int D) {
    int h = 0;
    while (D >> (h + 1)) ++h;
    return 1 << h;
}

__device__ __forceinline__ void rot2(float2& a0, float2& a1, float c, float s) {
    float t0x = s * a1.x, t0y = s * a1.y;
    float t1x = s * a0.x, t1y = s * a0.y;
    float n0x = fmaf(c, a0.x, -t0x), n0y = fmaf(c, a0.y, -t0y);
    float n1x = fmaf(c, a1.x,  t1x), n1y = fmaf(c, a1.y,  t1y);
    a0.x = n0x; a0.y = n0y;
    a1.x = n1x; a1.y = n1y;
}

template<int D, u32 PM>
__device__ __forceinline__ void gateGM(float2 (&am)[32], float c, float s, u32 sB) {
    constexpr int H = hbit(D);
    float sp = sB ? -s : s;
    #pragma unroll
    for (int r = 0; r < 32; ++r)
        if (!(r & H)) {
            if ((PM >> r) & 1) rot2(am[r], am[r ^ D], c, -sp);
            else               rot2(am[r], am[r ^ D], c,  sp);
        }
}

// ---------- thread-base helpers (per pass, ltid in [0,512)) ----------
__device__ __forceinline__ u32 B2of(int ltid) { return (((u32)ltid & 1u) << 1) | (((u32)ltid >> 1) << 6); }
__device__ __forceinline__ u32 B3of(int ltid) { return ((u32)ltid & 63u) | (((u32)ltid >> 6) << 11); }
__device__ __forceinline__ u32 B4of(int ltid) { return ((u32)ltid & 3u) | (((u32)ltid >> 2) << 7); }
__device__ __forceinline__ u32 B5of(int ltid) { return (((u32)ltid & 0xFFu) << 2) | (((u32)ltid >> 8) << 13); }
__device__ __forceinline__ u32 B7of(int ltid) { return ((u32)ltid & 0x7Fu) | (((u32)ltid >> 7) << 12); }

// ---------- pass components (all bodies verbatim from R4's verified kernel) ----------
__device__ __forceinline__ void doG1(float2 (&am)[32], const float* angC, const float* angS) {
    gateGM< 1, 0>(am, angC[ 0], angS[ 0], 0);
    gateGM< 2, 0>(am, angC[ 1], angS[ 1], 0);
    gateGM< 4, 0>(am, angC[11], angS[11], 0);
    gateGM< 8, 0>(am, angC[12], angS[12], 0);
    gateGM<16, 0>(am, angC[13], angS[13], 0);
}
__device__ __forceinline__ void doW1(int ltid, float* smem, float2 (&am)[32]) {
    float4* stv = (float4*)smem;
    u32 base = swzN((u32)ltid << 2);
    bool sw = (((ltid >> 2) ^ (ltid >> 3)) & 1) != 0;
    #pragma unroll
    for (int h = 0; h < 8; ++h)
        #pragma unroll
        for (int m = 0; m < 2; ++m) {
            u32 idx = (base ^ swzN(((u32)h << 11) | ((u32)m << 1))) >> 1;
            int r = h * 4 + m * 2;
            float2 a0 = am[r], a1 = am[r + 1];
            stv[idx] = sw ? make_float4(a1.x, a1.y, a0.x, a0.y)
                          : make_float4(a0.x, a0.y, a1.x, a1.y);
        }
}
__device__ __forceinline__ void doR2(int ltid, float* smem, float2 (&am)[32]) {
    float4* stv = (float4*)smem;
    u32 base = swzN(B2of(ltid));
    #pragma unroll
    for (int h = 0; h < 16; ++h) {
        u32 idx = (base ^ swzN((u32)h << 2)) >> 1;
        float4 v = stv[idx];
        if (((h >> 2) ^ (h >> 3)) & 1) {
            am[h * 2 + 1] = make_float2(v.x, v.y);
            am[h * 2]     = make_float2(v.z, v.w);
        } else {
            am[h * 2]     = make_float2(v.x, v.y);
            am[h * 2 + 1] = make_float2(v.z, v.w);
        }
    }
}
__device__ __forceinline__ void doW2(int ltid, float* smem, float2 (&am)[32]) {
    float4* stv = (float4*)smem;
    u32 base = swzN(B2of(ltid));
    #pragma unroll
    for (int h = 0; h < 16; ++h) {
        u32 idx = (base ^ swzN((u32)h << 2)) >> 1;
        float2 a0 = am[h * 2], a1 = am[h * 2 + 1];
        if (((h >> 2) ^ (h >> 3)) & 1) stv[idx] = make_float4(a1.x, a1.y, a0.x, a0.y);
        else                           stv[idx] = make_float4(a0.x, a0.y, a1.x, a1.y);
    }
}
__device__ __forceinline__ void doG2a(float2 (&am)[32], const float* angC, const float* angS) {
    gateGM< 2, 0>(am, angC[2], angS[2], 0);
    gateGM< 4, 0>(am, angC[3], angS[3], 0);
}
__device__ __forceinline__ void doG2b(float2 (&am)[32], const float* angC, const float* angS) {
    gateGM< 8, 0>(am, angC[4], angS[4], 0);
    gateGM<16, 0>(am, angC[5], angS[5], 0);
}
__device__ __forceinline__ void doR3(int ltid, float* smem, float2 (&am)[32]) {
    float2* st2 = (float2*)smem;
    u32 base = swzN(B3of(ltid));
    #pragma unroll
    for (int j = 0; j < 32; ++j) am[j] = st2[base ^ swzN((u32)j << 6)];
}
__device__ __forceinline__ void doW3(int ltid, float* smem, float2 (&am)[32]) {
    float2* st2 = (float2*)smem;
    u32 base = swzN(B3of(ltid));
    #pragma unroll
    for (int j = 0; j < 32; ++j) st2[base ^ swzN((u32)j << 6)] = am[j];
}
__device__ __forceinline__ void doG3a(float2 (&am)[32], const float* angC, const float* angS) {
    gateGM< 1, 0>(am, angC[ 6], angS[ 6], 0);
    gateGM< 2, 0>(am, angC[ 7], angS[ 7], 0);
    gateGM< 4, 0>(am, angC[ 8], angS[ 8], 0);
    gateGM< 8, 0>(am, angC[ 9], angS[ 9], 0);
    gateGM<16, 0>(am, angC[10], angS[10], 0);
}
__device__ __forceinline__ void doG3b(int ltid, float2 (&am)[32], const float* angC, const float* angS) {
    u32 z1 = mmap(B3of(ltid));
    gateGM< 3, parmask(PV3, 1,  7)>(am, angC[16 +  7], angS[16 +  7], (z1 >>  7) & 1u);
    gateGM< 6, parmask(PV3, 1,  8)>(am, angC[16 +  8], angS[16 +  8], (z1 >>  8) & 1u);
    gateGM<12, parmask(PV3, 1,  9)>(am, angC[16 +  9], angS[16 +  9], (z1 >>  9) & 1u);
    gateGM<24, parmask(PV3, 1, 10)>(am, angC[16 + 10], angS[16 + 10], (z1 >> 10) & 1u);
}
__device__ __forceinline__ void doR4(int ltid, float* smem, float2 (&am)[32]) {
    float2* st2 = (float2*)smem;
    u32 base = swzN(B4of(ltid));
    #pragma unroll
    for (int r = 0; r < 32; ++r) am[r] = st2[base ^ swzN(moff(PV4, r))];
}
__device__ __forceinline__ void doW4(int ltid, float* smem, float2 (&am)[32]) {
    float2* st2 = (float2*)smem;
    u32 base = swzN(B4of(ltid));
    #pragma unroll
    for (int r = 0; r < 32; ++r) st2[base ^ swzN(moff(PV4, r))] = am[r];
}
__device__ __forceinline__ void doG4a(int ltid, float2 (&am)[32], const float* angC, const float* angS) {
    u32 z1 = mmap(B4of(ltid));
    gateGM< 1, parmask(PV4, 1, 2)>(am, angC[16 + 2], angS[16 + 2], (z1 >> 2) & 1u);
    gateGM< 2, parmask(PV4, 1, 3)>(am, angC[16 + 3], angS[16 + 3], (z1 >> 3) & 1u);
    gateGM< 4, parmask(PV4, 1, 4)>(am, angC[16 + 4], angS[16 + 4], (z1 >> 4) & 1u);
}
__device__ __forceinline__ void doG4b(int ltid, float2 (&am)[32], const float* angC, const float* angS) {
    u32 z1 = mmap(B4of(ltid));
    gateGM< 8, parmask(PV4, 1, 5)>(am, angC[16 + 5], angS[16 + 5], (z1 >> 5) & 1u);
    gateGM<16, parmask(PV4, 1, 6)>(am, angC[16 + 6], angS[16 + 6], (z1 >> 6) & 1u);
}
__device__ __forceinline__ void doR5(int ltid, float* smem, float2 (&am)[32]) {
    float2* st2 = (float2*)smem;
    u32 base = swzN(B5of(ltid));
    #pragma unroll
    for (int r = 0; r < 32; ++r) am[r] = st2[base ^ swzN(moff(PV5, r))];
}
__device__ __forceinline__ void doW5(int ltid, float* smem, float2 (&am)[32]) {
    float2* st2 = (float2*)smem;
    u32 base = swzN(B5of(ltid));
    #pragma unroll
    for (int r = 0; r < 32; ++r) st2[base ^ swzN(moff(PV5, r))] = am[r];
}
__device__ __forceinline__ void doG5a(int ltid, float2 (&am)[32], const float* angC, const float* angS) {
    u32 z1 = mmap(B5of(ltid));
    gateGM< 1, parmask(PV5, 1,  0)>(am, angC[16 +  0], angS[16 +  0], (z1 >>  0) & 1u);
    gateGM< 2, parmask(PV5, 1,  1)>(am, angC[16 +  1], angS[16 +  1], (z1 >>  1) & 1u);
    gateGM< 4, parmask(PV5, 1, 11)>(am, angC[16 + 11], angS[16 + 11], (z1 >> 11) & 1u);
    gateGM< 8, parmask(PV5, 1, 12)>(am, angC[16 + 12], angS[16 + 12], (z1 >> 12) & 1u);
    gateGM<16, parmask(PV5, 1, 13)>(am, angC[16 + 13], angS[16 + 13], (z1 >> 13) & 1u);
}
__device__ __forceinline__ void doG5b(int ltid, float2 (&am)[32], const float* angC, const float* angS) {
    u32 z2 = mpow(B5of(ltid), 2);
    gateGM<25, parmask(PV5, 2,  0)>(am, angC[32 +  0], angS[32 +  0], (z2 >>  0) & 1u);
    gateGM< 3, parmask(PV5, 2,  1)>(am, angC[32 +  1], angS[32 +  1], (z2 >>  1) & 1u);
    gateGM<12, parmask(PV5, 2, 12)>(am, angC[32 + 12], angS[32 + 12], (z2 >> 12) & 1u);
    gateGM<24, parmask(PV5, 2, 13)>(am, angC[32 + 13], angS[32 + 13], (z2 >> 13) & 1u);
}
__device__ __forceinline__ void doR6(int ltid, float* smem, float2 (&am)[32]) {
    float2* st2 = (float2*)smem;
    u32 base = swzN(B4of(ltid));
    #pragma unroll
    for (int r = 0; r < 32; ++r) am[r] = st2[base ^ swzN(moff(PV6, r))];
}
__device__ __forceinline__ void doW6(int ltid, float* smem, float2 (&am)[32]) {
    float2* st2 = (float2*)smem;
    u32 base = swzN(B4of(ltid));
    #pragma unroll
    for (int r = 0; r < 32; ++r) st2[base ^ swzN(moff(PV6, r))] = am[r];
}
__device__ __forceinline__ void doG6a(int ltid, float2 (&am)[32], const float* angC, const float* angS) {
    u32 z2 = mpow(B4of(ltid), 2);
    gateGM< 1, parmask(PV6, 2, 2)>(am, angC[32 + 2], angS[32 + 2], (z2 >> 2) & 1u);
    gateGM< 2, parmask(PV6, 2, 3)>(am, angC[32 + 3], angS[32 + 3], (z2 >> 3) & 1u);
    gateGM< 4, parmask(PV6, 2, 4)>(am, angC[32 + 4], angS[32 + 4], (z2 >> 4) & 1u);
}
__device__ __forceinline__ void doG6b(int ltid, float2 (&am)[32], const float* angC, const float* angS) {
    u32 z2 = mpow(B4of(ltid), 2);
    gateGM< 8, parmask(PV6, 2, 5)>(am, angC[32 + 5], angS[32 + 5], (z2 >> 5) & 1u);
    gateGM<16, parmask(PV6, 2, 6)>(am, angC[32 + 6], angS[32 + 6], (z2 >> 6) & 1u);
}
__device__ __forceinline__ void doR7(int ltid, float* smem, float2 (&am)[32]) {
    float2* st2 = (float2*)smem;
    u32 base = swzN(B7of(ltid));
    #pragma unroll
    for (int r = 0; r < 32; ++r) am[r] = st2[base ^ swzN(moff(PV7, r))];
}
__device__ __forceinline__ void doG7(int ltid, float2 (&am)[32], const float* angC, const float* angS) {
    u32 z2 = mpow(B7of(ltid), 2);
    gateGM< 1, parmask(PV7, 2,  7)>(am, angC[32 +  7], angS[32 +  7], (z2 >>  7) & 1u);
    gateGM< 2, parmask(PV7, 2,  8)>(am, angC[32 +  8], angS[32 +  8], (z2 >>  8) & 1u);
    gateGM< 4, parmask(PV7, 2,  9)>(am, angC[32 +  9], angS[32 +  9], (z2 >>  9) & 1u);
    gateGM< 8, parmask(PV7, 2, 10)>(am, angC[32 + 10], angS[32 + 10], (z2 >> 10) & 1u);
    gateGM<16, parmask(PV7, 2, 11)>(am, angC[32 + 11], angS[32 + 11], (z2 >> 11) & 1u);
}
__device__ __forceinline__ void doMeas(int ltid, float2 (&am)[32], const float* lutLo,
                                       const float* lutHi, float& acc, float W0) {
    u32 wB = mpow(B7of(ltid), 3);
    #pragma unroll
    for (int r = 0; r < 32; ++r) {
        u32 w = wB ^ mpow(moff(PV7, r), 3);
        float p  = fmaf(am[r].x, am[r].x, am[r].y * am[r].y);
        float wv = W0 - 2.0f * (lutLo[w & 127u] + lutHi[w >> 7]);
        acc = fmaf(wv, p, acc);
    }
}

// Two wave-groups (A: tid<512, B: tid>=512), each simulating its own batch state
// with R4's verified 7-pass schedule; ONE 128KB LDS buffer ping-pongs ownership.
// Every phase pairs one group's LDS flood with the other's register-only gates;
// full block barrier at every ownership handoff (race-free by construction).
__global__ __launch_bounds__(NT, 1) void qsim_kernel(
    const float* __restrict__ sreal, const float* __restrict__ simag,
    const float* __restrict__ wts,   const float* __restrict__ hw,
    const float* __restrict__ hb,    float* __restrict__ out, int batch)
{
    extern __shared__ float smem[];
    float* angC   = smem + 32768;
    float* angS   = angC + 48;
    float* lutLo  = angS + 48;
    float* lutHi  = lutLo + 128;
    float* redbuf = lutHi + 128;

    int tid  = threadIdx.x;
    bool ga  = tid < 512;
    int ltid = tid & 511;
    int b    = blockIdx.x * 2 + (ga ? 0 : 1);
    if (b >= batch) b = batch - 1;

    // global load, P1 layout: float4 (h<<9)|ltid covers p = (h<<11)|(ltid<<2)|{0..3}
    const float4* pr = (const float4*)(sreal + (size_t)b * DIM);
    const float4* pi = (const float4*)(simag + (size_t)b * DIM);
    float2 am[32];
    #pragma unroll
    for (int h = 0; h < 8; ++h) {
        float4 r = pr[(h << 9) | ltid];
        float4 i = pi[(h << 9) | ltid];
        am[h * 4 + 0] = make_float2(r.x, i.x);
        am[h * 4 + 1] = make_float2(r.y, i.y);
        am[h * 4 + 2] = make_float2(r.z, i.z);
        am[h * 4 + 3] = make_float2(r.w, i.w);
    }

    // block-uniform setup (low tids only): summed half-angles + head LUTs
    if (tid < 42) {
        int l = tid / 14, bb = tid % 14, q = 13 - bb;
        float a = 0.5f * (wts[l * 42 + q] + wts[l * 42 + 14 + q] + wts[l * 42 + 28 + q]);
        angC[l * 16 + bb] = cosf(a);
        angS[l * 16 + bb] = sinf(a);
    } else if (tid >= 64 && tid < 192) {
        int i = tid - 64;
        float ssum = 0.f;
        for (int bb = 0; bb < 7; ++bb) if ((i >> bb) & 1) ssum += hw[13 - bb];
        lutLo[i] = ssum;
    } else if (tid >= 192 && tid < 320) {
        int i = tid - 192;
        float ssum = 0.f;
        for (int bb = 0; bb < 7; ++bb) if ((i >> bb) & 1) ssum += hw[6 - bb];
        lutHi[i] = ssum;
    }

    __syncthreads();
    float W0  = lutLo[127] + lutHi[127];
    float acc = 0.f;

    // ---- ping-pong schedule: [phase work] + barrier, uniform control flow ----
    // ph0
    if (ga) { doG1(am, angC, angS); doW1(ltid, smem, am); }
    else    { doG1(am, angC, angS); }
    __syncthreads();
    // ph1
    if (ga) { doR2(ltid, smem, am); }
    __syncthreads();
    // ph2
    if (ga) { doG2a(am, angC, angS); } else { doW1(ltid, smem, am); }
    __syncthreads();
    // ph3
    if (ga) { doG2b(am, angC, angS); } else { doR2(ltid, smem, am); }
    __syncthreads();
    // ph4
    if (ga) { doW2(ltid, smem, am); } else { doG2a(am, angC, angS); }
    __syncthreads();
    // ph5
    if (ga) { doR3(ltid, smem, am); } else { doG2b(am, angC, angS); }
    __syncthreads();
    // ph6
    if (ga) { doG3a(am, angC, angS); } else { doW2(ltid, smem, am); }
    __syncthreads();
    // ph7
    if (ga) { doG3b(ltid, am, angC, angS); } else { doR3(ltid, smem, am); }
    __syncthreads();
    // ph8
    if (ga) { doW3(ltid, smem, am); } else { doG3a(am, angC, angS); }
    __syncthreads();
    // ph9
    if (ga) { doR4(ltid, smem, am); } else { doG3b(ltid, am, angC, angS); }
    __syncthreads();
    // ph10
    if (ga) { doG4a(ltid, am, angC, angS); } else { doW3(ltid, smem, am); }
    __syncthreads();
    // ph11
    if (ga) { doG4b(ltid, am, angC, angS); } else { doR4(ltid, smem, am); }
    __syncthreads();
    // ph12
    if (ga) { doW4(ltid, smem, am); } else { doG4a(ltid, am, angC, angS); }
    __syncthreads();
    // ph13
    if (ga) { doR5(ltid, smem, am); } else { doG4b(ltid, am, angC, angS); }
    __syncthreads();
    // ph14
    if (ga) { doG5a(ltid, am, angC, angS); } else { doW4(ltid, smem, am); }
    __syncthreads();
    // ph15
    if (ga) { doG5b(ltid, am, angC, angS); } else { doR5(ltid, smem, am); }
    __syncthreads();
    // ph16
    if (ga) { doW5(ltid, smem, am); } else { doG5a(ltid, am, angC, angS); }
    __syncthreads();
    // ph17
    if (ga) { doR6(ltid, smem, am); } else { doG5b(ltid, am, angC, angS); }
    __syncthreads();
    // ph18
    if (ga) { doG6a(ltid, am, angC, angS); } else { doW5(ltid, smem, am); }
    __syncthreads();
    // ph19
    if (ga) { doG6b(ltid, am, angC, angS); } else { doR6(ltid, smem, am); }
    __syncthreads();
    // ph20
    if (ga) { doW6(ltid, smem, am); } else { doG6a(ltid, am, angC, angS); }
    __syncthreads();
    // ph21
    if (ga) { doR7(ltid, smem, am); } else { doG6b(ltid, am, angC, angS); }
    __syncthreads();
    // ph22
    if (ga) { doG7(ltid, am, angC, angS); doMeas(ltid, am, lutLo, lutHi, acc, W0); }
    else    { doW6(ltid, smem, am); }
    __syncthreads();
    // ph23
    if (!ga) { doR7(ltid, smem, am); }
    __syncthreads();
    // ph24 (no trailing barrier needed before reduction's own sync)
    if (!ga) { doG7(ltid, am, angC, angS); doMeas(ltid, am, lutLo, lutHi, acc, W0); }

    // per-group reduction: wave shuffle -> redbuf[16] -> two writers
    #pragma unroll
    for (int off = 32; off > 0; off >>= 1) acc += __shfl_xor(acc, off, 64);
    if ((tid & 63) == 0) redbuf[tid >> 6] = acc;
    __syncthreads();
    if (tid == 0) {
        float t = hb[0];
        #pragma unroll
        for (int i = 0; i < 8; ++i) t += redbuf[i];
        out[blockIdx.x * 2] = t;
    } else if (tid == 512 && blockIdx.x * 2 + 1 < batch) {
        float t = hb[0];
        #pragma unroll
        for (int i = 0; i < 8; ++i) t += redbuf[8 + i];
        out[blockIdx.x * 2 + 1] = t;
    }
}

extern "C" void kernel_launch(void* const* d_in, const int* in_sizes, int n_in,
                              void* d_out, int out_size, void* d_ws, size_t ws_size,
                              hipStream_t stream)
{
    const float* sreal = (const float*)d_in[0];
    const float* simag = (const float*)d_in[1];
    const float* wts   = (const float*)d_in[2];
    const float* hw    = (const float*)d_in[3];
    const float* hb    = (const float*)d_in[4];
    float* out = (float*)d_out;

    int batch = in_sizes[0] / DIM;
    int nblk  = (batch + 1) / 2;
    size_t smem_bytes = (32768 + 48 + 48 + 128 + 128 + 16) * sizeof(float);  // 132.5 KB < 160 KB

    (void)hipFuncSetAttribute((const void*)qsim_kernel,
                              hipFuncAttributeMaxDynamicSharedMemorySize, (int)smem_bytes);
    qsim_kernel<<<dim3(nblk), dim3(NT), smem_bytes, stream>>>(sreal, simag, wts, hw, hb, out, batch);
}

// Round 6
// 330.378 us; speedup vs baseline: 1.0046x; 1.0046x over previous
//
#include <hip/hip_runtime.h>

typedef unsigned int u32;

#define DIM 16384
#define NT  1024

// Swizzle v4 (R3/R4-verified).
__host__ __device__ constexpr u32 swzN(u32 d) {
    u32 b0 = ((d >> 4) ^ (d >> 5)) & 1u;
    u32 b1 = (d >> 4) & 1u;
    u32 b2 = ((d >> 7) ^ (d >> 8)) & 1u;
    u32 b3 = ((d >> 6) ^ (d >> 8)) & 1u;
    return d ^ b0 ^ (b1 << 1) ^ (b2 << 2) ^ (b3 << 3);
}

// CNOT-ring basis map (HW-validated).
__host__ __device__ constexpr u32 mmap(u32 y) {
    u32 s = y;
    s ^= s >> 1; s ^= s >> 2; s ^= s >> 4; s ^= s >> 8;
    return (s & 0x1FFFu) | (((s ^ (y >> 13)) & 1u) << 13);
}
__host__ __device__ constexpr u32 mpow(u32 x, int L) {
    for (int i = 0; i < L; ++i) x = mmap(x);
    return x;
}

// 7-pass schedule (R4-verified, proven minimal: 3+3+3-2).
constexpr u32 PV3[5] = {0x040, 0x080, 0x100, 0x200, 0x400};
constexpr u32 PV4[5] = {0x006, 0x00C, 0x018, 0x030, 0x060};
constexpr u32 PV5[5] = {0x3001, 0x0003, 0x0C00, 0x1800, 0x3000};
constexpr u32 PV6[5] = {0x005, 0x00A, 0x014, 0x028, 0x050};
constexpr u32 PV7[5] = {0x0A0, 0x140, 0x280, 0x500, 0xA00};

__host__ __device__ constexpr u32 moff(const u32* v, int r) {
    u32 m = 0;
    for (int i = 0; i < 5; ++i) if ((r >> i) & 1) m ^= v[i];
    return m;
}
__host__ __device__ constexpr u32 parmask(const u32* v, int L, int b) {
    u32 pm = 0;
    for (int r = 0; r < 32; ++r)
        pm |= ((mpow(moff(v, r), L) >> b) & 1u) << r;
    return pm;
}
__host__ __device__ constexpr int hbit(int D) {
    int h = 0;
    while (D >> (h + 1)) ++h;
    return 1 << h;
}

__device__ __forceinline__ void rot2(float2& a0, float2& a1, float c, float s) {
    float t0x = s * a1.x, t0y = s * a1.y;
    float t1x = s * a0.x, t1y = s * a0.y;
    float n0x = fmaf(c, a0.x, -t0x), n0y = fmaf(c, a0.y, -t0y);
    float n1x = fmaf(c, a1.x,  t1x), n1y = fmaf(c, a1.y,  t1y);
    a0.x = n0x; a0.y = n0y;
    a1.x = n1x; a1.y = n1y;
}

template<int D, u32 PM>
__device__ __forceinline__ void gateGM(float2 (&am)[32], float c, float s, u32 sB) {
    constexpr int H = hbit(D);
    float sp = sB ? -s : s;
    #pragma unroll
    for (int r = 0; r < 32; ++r)
        if (!(r & H)) {
            if ((PM >> r) & 1) rot2(am[r], am[r ^ D], c, -sp);
            else               rot2(am[r], am[r ^ D], c,  sp);
        }
}

// ---------- thread-base helpers (per pass, ltid in [0,512)) ----------
__device__ __forceinline__ u32 B2of(int ltid) { return (((u32)ltid & 1u) << 1) | (((u32)ltid >> 1) << 6); }
__device__ __forceinline__ u32 B3of(int ltid) { return ((u32)ltid & 63u) | (((u32)ltid >> 6) << 11); }
__device__ __forceinline__ u32 B4of(int ltid) { return ((u32)ltid & 3u) | (((u32)ltid >> 2) << 7); }
__device__ __forceinline__ u32 B5of(int ltid) { return (((u32)ltid & 0xFFu) << 2) | (((u32)ltid >> 8) << 13); }
__device__ __forceinline__ u32 B7of(int ltid) { return ((u32)ltid & 0x7Fu) | (((u32)ltid >> 7) << 12); }

// ---------- pass components (bodies verbatim from R4's verified kernel) ----------
__device__ __forceinline__ void doG1(float2 (&am)[32], const float* angC, const float* angS) {
    gateGM< 1, 0>(am, angC[ 0], angS[ 0], 0);
    gateGM< 2, 0>(am, angC[ 1], angS[ 1], 0);
    gateGM< 4, 0>(am, angC[11], angS[11], 0);
    gateGM< 8, 0>(am, angC[12], angS[12], 0);
    gateGM<16, 0>(am, angC[13], angS[13], 0);
}
__device__ __forceinline__ void doW1(int ltid, float* smem, float2 (&am)[32]) {
    float4* stv = (float4*)smem;
    u32 base = swzN((u32)ltid << 2);
    bool sw = (((ltid >> 2) ^ (ltid >> 3)) & 1) != 0;
    #pragma unroll
    for (int h = 0; h < 8; ++h)
        #pragma unroll
        for (int m = 0; m < 2; ++m) {
            u32 idx = (base ^ swzN(((u32)h << 11) | ((u32)m << 1))) >> 1;
            int r = h * 4 + m * 2;
            float2 a0 = am[r], a1 = am[r + 1];
            stv[idx] = sw ? make_float4(a1.x, a1.y, a0.x, a0.y)
                          : make_float4(a0.x, a0.y, a1.x, a1.y);
        }
}
__device__ __forceinline__ void doR2(int ltid, float* smem, float2 (&am)[32]) {
    float4* stv = (float4*)smem;
    u32 base = swzN(B2of(ltid));
    #pragma unroll
    for (int h = 0; h < 16; ++h) {
        u32 idx = (base ^ swzN((u32)h << 2)) >> 1;
        float4 v = stv[idx];
        if (((h >> 2) ^ (h >> 3)) & 1) {
            am[h * 2 + 1] = make_float2(v.x, v.y);
            am[h * 2]     = make_float2(v.z, v.w);
        } else {
            am[h * 2]     = make_float2(v.x, v.y);
            am[h * 2 + 1] = make_float2(v.z, v.w);
        }
    }
}
__device__ __forceinline__ void doW2(int ltid, float* smem, float2 (&am)[32]) {
    float4* stv = (float4*)smem;
    u32 base = swzN(B2of(ltid));
    #pragma unroll
    for (int h = 0; h < 16; ++h) {
        u32 idx = (base ^ swzN((u32)h << 2)) >> 1;
        float2 a0 = am[h * 2], a1 = am[h * 2 + 1];
        if (((h >> 2) ^ (h >> 3)) & 1) stv[idx] = make_float4(a1.x, a1.y, a0.x, a0.y);
        else                           stv[idx] = make_float4(a0.x, a0.y, a1.x, a1.y);
    }
}
__device__ __forceinline__ void doG2a(float2 (&am)[32], const float* angC, const float* angS) {
    gateGM< 2, 0>(am, angC[2], angS[2], 0);
    gateGM< 4, 0>(am, angC[3], angS[3], 0);
}
__device__ __forceinline__ void doG2b(float2 (&am)[32], const float* angC, const float* angS) {
    gateGM< 8, 0>(am, angC[4], angS[4], 0);
    gateGM<16, 0>(am, angC[5], angS[5], 0);
}
__device__ __forceinline__ void doR3(int ltid, float* smem, float2 (&am)[32]) {
    float2* st2 = (float2*)smem;
    u32 base = swzN(B3of(ltid));
    #pragma unroll
    for (int j = 0; j < 32; ++j) am[j] = st2[base ^ swzN((u32)j << 6)];
}
__device__ __forceinline__ void doW3(int ltid, float* smem, float2 (&am)[32]) {
    float2* st2 = (float2*)smem;
    u32 base = swzN(B3of(ltid));
    #pragma unroll
    for (int j = 0; j < 32; ++j) st2[base ^ swzN((u32)j << 6)] = am[j];
}
__device__ __forceinline__ void doG3a(float2 (&am)[32], const float* angC, const float* angS) {
    gateGM< 1, 0>(am, angC[ 6], angS[ 6], 0);
    gateGM< 2, 0>(am, angC[ 7], angS[ 7], 0);
    gateGM< 4, 0>(am, angC[ 8], angS[ 8], 0);
    gateGM< 8, 0>(am, angC[ 9], angS[ 9], 0);
    gateGM<16, 0>(am, angC[10], angS[10], 0);
}
__device__ __forceinline__ void doG3b(int ltid, float2 (&am)[32], const float* angC, const float* angS) {
    u32 z1 = mmap(B3of(ltid));
    gateGM< 3, parmask(PV3, 1,  7)>(am, angC[16 +  7], angS[16 +  7], (z1 >>  7) & 1u);
    gateGM< 6, parmask(PV3, 1,  8)>(am, angC[16 +  8], angS[16 +  8], (z1 >>  8) & 1u);
    gateGM<12, parmask(PV3, 1,  9)>(am, angC[16 +  9], angS[16 +  9], (z1 >>  9) & 1u);
    gateGM<24, parmask(PV3, 1, 10)>(am, angC[16 + 10], angS[16 + 10], (z1 >> 10) & 1u);
}
__device__ __forceinline__ void doR4(int ltid, float* smem, float2 (&am)[32]) {
    float2* st2 = (float2*)smem;
    u32 base = swzN(B4of(ltid));
    #pragma unroll
    for (int r = 0; r < 32; ++r) am[r] = st2[base ^ swzN(moff(PV4, r))];
}
__device__ __forceinline__ void doW4(int ltid, float* smem, float2 (&am)[32]) {
    float2* st2 = (float2*)smem;
    u32 base = swzN(B4of(ltid));
    #pragma unroll
    for (int r = 0; r < 32; ++r) st2[base ^ swzN(moff(PV4, r))] = am[r];
}
__device__ __forceinline__ void doG4a(int ltid, float2 (&am)[32], const float* angC, const float* angS) {
    u32 z1 = mmap(B4of(ltid));
    gateGM< 1, parmask(PV4, 1, 2)>(am, angC[16 + 2], angS[16 + 2], (z1 >> 2) & 1u);
    gateGM< 2, parmask(PV4, 1, 3)>(am, angC[16 + 3], angS[16 + 3], (z1 >> 3) & 1u);
    gateGM< 4, parmask(PV4, 1, 4)>(am, angC[16 + 4], angS[16 + 4], (z1 >> 4) & 1u);
}
__device__ __forceinline__ void doG4b(int ltid, float2 (&am)[32], const float* angC, const float* angS) {
    u32 z1 = mmap(B4of(ltid));
    gateGM< 8, parmask(PV4, 1, 5)>(am, angC[16 + 5], angS[16 + 5], (z1 >> 5) & 1u);
    gateGM<16, parmask(PV4, 1, 6)>(am, angC[16 + 6], angS[16 + 6], (z1 >> 6) & 1u);
}
__device__ __forceinline__ void doR5(int ltid, float* smem, float2 (&am)[32]) {
    float2* st2 = (float2*)smem;
    u32 base = swzN(B5of(ltid));
    #pragma unroll
    for (int r = 0; r < 32; ++r) am[r] = st2[base ^ swzN(moff(PV5, r))];
}
__device__ __forceinline__ void doW5(int ltid, float* smem, float2 (&am)[32]) {
    float2* st2 = (float2*)smem;
    u32 base = swzN(B5of(ltid));
    #pragma unroll
    for (int r = 0; r < 32; ++r) st2[base ^ swzN(moff(PV5, r))] = am[r];
}
__device__ __forceinline__ void doG5a(int ltid, float2 (&am)[32], const float* angC, const float* angS) {
    u32 z1 = mmap(B5of(ltid));
    gateGM< 1, parmask(PV5, 1,  0)>(am, angC[16 +  0], angS[16 +  0], (z1 >>  0) & 1u);
    gateGM< 2, parmask(PV5, 1,  1)>(am, angC[16 +  1], angS[16 +  1], (z1 >>  1) & 1u);
    gateGM< 4, parmask(PV5, 1, 11)>(am, angC[16 + 11], angS[16 + 11], (z1 >> 11) & 1u);
    gateGM< 8, parmask(PV5, 1, 12)>(am, angC[16 + 12], angS[16 + 12], (z1 >> 12) & 1u);
    gateGM<16, parmask(PV5, 1, 13)>(am, angC[16 + 13], angS[16 + 13], (z1 >> 13) & 1u);
}
__device__ __forceinline__ void doG5b(int ltid, float2 (&am)[32], const float* angC, const float* angS) {
    u32 z2 = mpow(B5of(ltid), 2);
    gateGM<25, parmask(PV5, 2,  0)>(am, angC[32 +  0], angS[32 +  0], (z2 >>  0) & 1u);
    gateGM< 3, parmask(PV5, 2,  1)>(am, angC[32 +  1], angS[32 +  1], (z2 >>  1) & 1u);
    gateGM<12, parmask(PV5, 2, 12)>(am, angC[32 + 12], angS[32 + 12], (z2 >> 12) & 1u);
    gateGM<24, parmask(PV5, 2, 13)>(am, angC[32 + 13], angS[32 + 13], (z2 >> 13) & 1u);
}
__device__ __forceinline__ void doR6(int ltid, float* smem, float2 (&am)[32]) {
    float2* st2 = (float2*)smem;
    u32 base = swzN(B4of(ltid));
    #pragma unroll
    for (int r = 0; r < 32; ++r) am[r] = st2[base ^ swzN(moff(PV6, r))];
}
__device__ __forceinline__ void doW6(int ltid, float* smem, float2 (&am)[32]) {
    float2* st2 = (float2*)smem;
    u32 base = swzN(B4of(ltid));
    #pragma unroll
    for (int r = 0; r < 32; ++r) st2[base ^ swzN(moff(PV6, r))] = am[r];
}
__device__ __forceinline__ void doG6a(int ltid, float2 (&am)[32], const float* angC, const float* angS) {
    u32 z2 = mpow(B4of(ltid), 2);
    gateGM< 1, parmask(PV6, 2, 2)>(am, angC[32 + 2], angS[32 + 2], (z2 >> 2) & 1u);
    gateGM< 2, parmask(PV6, 2, 3)>(am, angC[32 + 3], angS[32 + 3], (z2 >> 3) & 1u);
    gateGM< 4, parmask(PV6, 2, 4)>(am, angC[32 + 4], angS[32 + 4], (z2 >> 4) & 1u);
}
__device__ __forceinline__ void doG6b(int ltid, float2 (&am)[32], const float* angC, const float* angS) {
    u32 z2 = mpow(B4of(ltid), 2);
    gateGM< 8, parmask(PV6, 2, 5)>(am, angC[32 + 5], angS[32 + 5], (z2 >> 5) & 1u);
    gateGM<16, parmask(PV6, 2, 6)>(am, angC[32 + 6], angS[32 + 6], (z2 >> 6) & 1u);
}
__device__ __forceinline__ void doR7(int ltid, float* smem, float2 (&am)[32]) {
    float2* st2 = (float2*)smem;
    u32 base = swzN(B7of(ltid));
    #pragma unroll
    for (int r = 0; r < 32; ++r) am[r] = st2[base ^ swzN(moff(PV7, r))];
}
__device__ __forceinline__ void doG7(int ltid, float2 (&am)[32], const float* angC, const float* angS) {
    u32 z2 = mpow(B7of(ltid), 2);
    gateGM< 1, parmask(PV7, 2,  7)>(am, angC[32 +  7], angS[32 +  7], (z2 >>  7) & 1u);
    gateGM< 2, parmask(PV7, 2,  8)>(am, angC[32 +  8], angS[32 +  8], (z2 >>  8) & 1u);
    gateGM< 4, parmask(PV7, 2,  9)>(am, angC[32 +  9], angS[32 +  9], (z2 >>  9) & 1u);
    gateGM< 8, parmask(PV7, 2, 10)>(am, angC[32 + 10], angS[32 + 10], (z2 >> 10) & 1u);
    gateGM<16, parmask(PV7, 2, 11)>(am, angC[32 + 11], angS[32 + 11], (z2 >> 11) & 1u);
}
__device__ __forceinline__ void doMeas(int ltid, float2 (&am)[32], const float* lutLo,
                                       const float* lutHi, float& acc, float W0) {
    u32 wB = mpow(B7of(ltid), 3);
    #pragma unroll
    for (int r = 0; r < 32; ++r) {
        u32 w = wB ^ mpow(moff(PV7, r), 3);
        float p  = fmaf(am[r].x, am[r].x, am[r].y * am[r].y);
        float wv = W0 - 2.0f * (lutLo[w & 127u] + lutHi[w >> 7]);
        acc = fmaf(wv, p, acc);
    }
}

// Two wave-groups (A: tid<512, B: tid>=512), each simulating its own batch state;
// ONE 128KB LDS buffer ping-pongs ownership. Every phase pairs one group's LDS
// flood with the other's register-only gates; full barrier at every handoff.
//
// R5 lesson: with a 1024-thread block the compiler's occupancy heuristic capped
// VGPRs at 64 (targeting 2 blocks/CU it can never get — 132.5KB LDS allows 1)
// and spilled am[32] to scratch (WRITE_SIZE 32KB -> 500MB). amdgpu_waves_per_eu(4,4)
// pins the budget at 512/4 = 128 VGPRs: exactly our one resident block.
__global__ __launch_bounds__(NT)
__attribute__((amdgpu_waves_per_eu(4, 4)))
void qsim_kernel(
    const float* __restrict__ sreal, const float* __restrict__ simag,
    const float* __restrict__ wts,   const float* __restrict__ hw,
    const float* __restrict__ hb,    float* __restrict__ out, int batch)
{
    extern __shared__ float smem[];
    float* angC   = smem + 32768;
    float* angS   = angC + 48;
    float* lutLo  = angS + 48;
    float* lutHi  = lutLo + 128;
    float* redbuf = lutHi + 128;

    int tid  = threadIdx.x;
    bool ga  = tid < 512;
    int ltid = tid & 511;
    int b    = blockIdx.x * 2 + (ga ? 0 : 1);
    if (b >= batch) b = batch - 1;

    // global load, P1 layout: float4 (h<<9)|ltid covers p = (h<<11)|(ltid<<2)|{0..3}
    const float4* pr = (const float4*)(sreal + (size_t)b * DIM);
    const float4* pi = (const float4*)(simag + (size_t)b * DIM);
    float2 am[32];
    #pragma unroll
    for (int h = 0; h < 8; ++h) {
        float4 r = pr[(h << 9) | ltid];
        float4 i = pi[(h << 9) | ltid];
        am[h * 4 + 0] = make_float2(r.x, i.x);
        am[h * 4 + 1] = make_float2(r.y, i.y);
        am[h * 4 + 2] = make_float2(r.z, i.z);
        am[h * 4 + 3] = make_float2(r.w, i.w);
    }

    // block-uniform setup (low tids only): summed half-angles + head LUTs
    if (tid < 42) {
        int l = tid / 14, bb = tid % 14, q = 13 - bb;
        float a = 0.5f * (wts[l * 42 + q] + wts[l * 42 + 14 + q] + wts[l * 42 + 28 + q]);
        angC[l * 16 + bb] = cosf(a);
        angS[l * 16 + bb] = sinf(a);
    } else if (tid >= 64 && tid < 192) {
        int i = tid - 64;
        float ssum = 0.f;
        for (int bb = 0; bb < 7; ++bb) if ((i >> bb) & 1) ssum += hw[13 - bb];
        lutLo[i] = ssum;
    } else if (tid >= 192 && tid < 320) {
        int i = tid - 192;
        float ssum = 0.f;
        for (int bb = 0; bb < 7; ++bb) if ((i >> bb) & 1) ssum += hw[6 - bb];
        lutHi[i] = ssum;
    }

    __syncthreads();
    float W0  = lutLo[127] + lutHi[127];
    float acc = 0.f;

    // ---- ping-pong schedule: [phase work] + barrier, uniform control flow ----
    // ph0
    if (ga) { doG1(am, angC, angS); doW1(ltid, smem, am); }
    else    { doG1(am, angC, angS); }
    __syncthreads();
    // ph1
    if (ga) { doR2(ltid, smem, am); }
    __syncthreads();
    // ph2
    if (ga) { doG2a(am, angC, angS); } else { doW1(ltid, smem, am); }
    __syncthreads();
    // ph3
    if (ga) { doG2b(am, angC, angS); } else { doR2(ltid, smem, am); }
    __syncthreads();
    // ph4
    if (ga) { doW2(ltid, smem, am); } else { doG2a(am, angC, angS); }
    __syncthreads();
    // ph5
    if (ga) { doR3(ltid, smem, am); } else { doG2b(am, angC, angS); }
    __syncthreads();
    // ph6
    if (ga) { doG3a(am, angC, angS); } else { doW2(ltid, smem, am); }
    __syncthreads();
    // ph7
    if (ga) { doG3b(ltid, am, angC, angS); } else { doR3(ltid, smem, am); }
    __syncthreads();
    // ph8
    if (ga) { doW3(ltid, smem, am); } else { doG3a(am, angC, angS); }
    __syncthreads();
    // ph9
    if (ga) { doR4(ltid, smem, am); } else { doG3b(ltid, am, angC, angS); }
    __syncthreads();
    // ph10
    if (ga) { doG4a(ltid, am, angC, angS); } else { doW3(ltid, smem, am); }
    __syncthreads();
    // ph11
    if (ga) { doG4b(ltid, am, angC, angS); } else { doR4(ltid, smem, am); }
    __syncthreads();
    // ph12
    if (ga) { doW4(ltid, smem, am); } else { doG4a(ltid, am, angC, angS); }
    __syncthreads();
    // ph13
    if (ga) { doR5(ltid, smem, am); } else { doG4b(ltid, am, angC, angS); }
    __syncthreads();
    // ph14
    if (ga) { doG5a(ltid, am, angC, angS); } else { doW4(ltid, smem, am); }
    __syncthreads();
    // ph15
    if (ga) { doG5b(ltid, am, angC, angS); } else { doR5(ltid, smem, am); }
    __syncthreads();
    // ph16
    if (ga) { doW5(ltid, smem, am); } else { doG5a(ltid, am, angC, angS); }
    __syncthreads();
    // ph17
    if (ga) { doR6(ltid, smem, am); } else { doG5b(ltid, am, angC, angS); }
    __syncthreads();
    // ph18
    if (ga) { doG6a(ltid, am, angC, angS); } else { doW5(ltid, smem, am); }
    __syncthreads();
    // ph19
    if (ga) { doG6b(ltid, am, angC, angS); } else { doR6(ltid, smem, am); }
    __syncthreads();
    // ph20
    if (ga) { doW6(ltid, smem, am); } else { doG6a(ltid, am, angC, angS); }
    __syncthreads();
    // ph21
    if (ga) { doR7(ltid, smem, am); } else { doG6b(ltid, am, angC, angS); }
    __syncthreads();
    // ph22
    if (ga) { doG7(ltid, am, angC, angS); doMeas(ltid, am, lutLo, lutHi, acc, W0); }
    else    { doW6(ltid, smem, am); }
    __syncthreads();
    // ph23
    if (!ga) { doR7(ltid, smem, am); }
    __syncthreads();
    // ph24
    if (!ga) { doG7(ltid, am, angC, angS); doMeas(ltid, am, lutLo, lutHi, acc, W0); }

    // per-group reduction: wave shuffle -> redbuf[16] -> two writers
    #pragma unroll
    for (int off = 32; off > 0; off >>= 1) acc += __shfl_xor(acc, off, 64);
    if ((tid & 63) == 0) redbuf[tid >> 6] = acc;
    __syncthreads();
    if (tid == 0) {
        float t = hb[0];
        #pragma unroll
        for (int i = 0; i < 8; ++i) t += redbuf[i];
        out[blockIdx.x * 2] = t;
    } else if (tid == 512 && blockIdx.x * 2 + 1 < batch) {
        float t = hb[0];
        #pragma unroll
        for (int i = 0; i < 8; ++i) t += redbuf[8 + i];
        out[blockIdx.x * 2 + 1] = t;
    }
}

extern "C" void kernel_launch(void* const* d_in, const int* in_sizes, int n_in,
                              void* d_out, int out_size, void* d_ws, size_t ws_size,
                              hipStream_t stream)
{
    const float* sreal = (const float*)d_in[0];
    const float* simag = (const float*)d_in[1];
    const float* wts   = (const float*)d_in[2];
    const float* hw    = (const float*)d_in[3];
    const float* hb    = (const float*)d_in[4];
    float* out = (float*)d_out;

    int batch = in_sizes[0] / DIM;
    int nblk  = (batch + 1) / 2;
    size_t smem_bytes = (32768 + 48 + 48 + 128 + 128 + 16) * sizeof(float);  // 132.5 KB < 160 KB

    (void)hipFuncSetAttribute((const void*)qsim_kernel,
                              hipFuncAttributeMaxDynamicSharedMemorySize, (int)smem_bytes);
    qsim_kernel<<<dim3(nblk), dim3(NT), smem_bytes, stream>>>(sreal, simag, wts, hw, hb, out, batch);
}

// Round 7
// 250.790 us; speedup vs baseline: 1.3234x; 1.3173x over previous
//
#include <hip/hip_runtime.h>

typedef unsigned int u32;

#define DIM 16384
#define NT  512

// Swizzle v4 (R3/R4-verified).
__host__ __device__ constexpr u32 swzN(u32 d) {
    u32 b0 = ((d >> 4) ^ (d >> 5)) & 1u;
    u32 b1 = (d >> 4) & 1u;
    u32 b2 = ((d >> 7) ^ (d >> 8)) & 1u;
    u32 b3 = ((d >> 6) ^ (d >> 8)) & 1u;
    return d ^ b0 ^ (b1 << 1) ^ (b2 << 2) ^ (b3 << 3);
}

// CNOT-ring basis map (HW-validated).
__host__ __device__ constexpr u32 mmap(u32 y) {
    u32 s = y;
    s ^= s >> 1; s ^= s >> 2; s ^= s >> 4; s ^= s >> 8;
    return (s & 0x1FFFu) | (((s ^ (y >> 13)) & 1u) << 13);
}
__host__ __device__ constexpr u32 mpow(u32 x, int L) {
    for (int i = 0; i < L; ++i) x = mmap(x);
    return x;
}

// 7-pass schedule (R4-verified, proven minimal).
constexpr u32 PV3[5] = {0x040, 0x080, 0x100, 0x200, 0x400};
constexpr u32 PV4[5] = {0x006, 0x00C, 0x018, 0x030, 0x060};
constexpr u32 PV5[5] = {0x3001, 0x0003, 0x0C00, 0x1800, 0x3000};
constexpr u32 PV6[5] = {0x005, 0x00A, 0x014, 0x028, 0x050};
constexpr u32 PV7[5] = {0x0A0, 0x140, 0x280, 0x500, 0xA00};

__host__ __device__ constexpr u32 moff(const u32* v, int r) {
    u32 m = 0;
    for (int i = 0; i < 5; ++i) if ((r >> i) & 1) m ^= v[i];
    return m;
}
__host__ __device__ constexpr u32 parmask(const u32* v, int L, int b) {
    u32 pm = 0;
    for (int r = 0; r < 32; ++r)
        pm |= ((mpow(moff(v, r), L) >> b) & 1u) << r;
    return pm;
}
__host__ __device__ constexpr int hbit(int D) {
    int h = 0;
    while (D >> (h + 1)) ++h;
    return 1 << h;
}
// Drop bit t of s (bit t is the transition's g-functional: constant per round).
__host__ __device__ constexpr u32 cmpt(u32 s, int t) {
    return (s & ((1u << t) - 1u)) | ((s >> (t + 1)) << t);
}

__device__ __forceinline__ void rot2(float2& a0, float2& a1, float c, float s) {
    float t0x = s * a1.x, t0y = s * a1.y;
    float t1x = s * a0.x, t1y = s * a0.y;
    float n0x = fmaf(c, a0.x, -t0x), n0y = fmaf(c, a0.y, -t0y);
    float n1x = fmaf(c, a1.x,  t1x), n1y = fmaf(c, a1.y,  t1y);
    a0.x = n0x; a0.y = n0y;
    a1.x = n1x; a1.y = n1y;
}

template<int D, u32 PM>
__device__ __forceinline__ void gateGM(float2 (&am)[32], float c, float s, u32 sB) {
    constexpr int H = hbit(D);
    float sp = sB ? -s : s;
    #pragma unroll
    for (int r = 0; r < 32; ++r)
        if (!(r & H)) {
            if ((PM >> r) & 1) rot2(am[r], am[r ^ D], c, -sp);
            else               rot2(am[r], am[r ^ D], c,  sp);
        }
}

// ---------- thread-base maps (re-derived R7 so every transition's g-bit is
// wave-uniform: g=e8 transitions round on tid6, g=e12 on tid7) ----------
// P2: tid0->y1, tid1,2->y6,7, tid6->y8, tid3,4,5->y9,10,11, tid7,8->y12,13
__device__ __forceinline__ u32 B2of(int t) {
    return ((u32)(t & 1) << 1) | ((u32)((t >> 1) & 3) << 6) | ((u32)((t >> 6) & 1) << 8)
         | ((u32)((t >> 3) & 7) << 9) | ((u32)((t >> 7) & 3) << 12);
}
// P3: tid0..5->y0..5, tid6,7,8->y11,12,13 (unchanged)
__device__ __forceinline__ u32 B3of(int t) { return ((u32)t & 63u) | (((u32)t >> 6) << 11); }
// P4/P6: tid0,1->y0,1, tid2->y7, tid6->y8, tid3,4,5->y9,10,11, tid7,8->y12,13
__device__ __forceinline__ u32 B4of(int t) {
    return (u32)(t & 3) | ((u32)((t >> 2) & 1) << 7) | ((u32)((t >> 6) & 1) << 8)
         | ((u32)((t >> 3) & 7) << 9) | ((u32)((t >> 7) & 3) << 12);
}
// P5: tid0..7->y2..9, tid8->y13 (unchanged; y8<-tid6)
__device__ __forceinline__ u32 B5of(int t) { return (((u32)t & 0xFFu) << 2) | (((u32)t >> 8) << 13); }
// P7: tid0..6->y0..6, tid7,8->y12,13 (unchanged; y12<-tid7)
__device__ __forceinline__ u32 B7of(int t) { return ((u32)t & 0x7Fu) | (((u32)t >> 7) << 12); }

// ---------- gates (R4-verified bodies; sign bits recomputed from new bases) ----------
__device__ __forceinline__ void doG1(float2 (&am)[32], const float* angC, const float* angS) {
    gateGM< 1, 0>(am, angC[ 0], angS[ 0], 0);
    gateGM< 2, 0>(am, angC[ 1], angS[ 1], 0);
    gateGM< 4, 0>(am, angC[11], angS[11], 0);
    gateGM< 8, 0>(am, angC[12], angS[12], 0);
    gateGM<16, 0>(am, angC[13], angS[13], 0);
}
__device__ __forceinline__ void doG2(float2 (&am)[32], const float* angC, const float* angS) {
    gateGM< 2, 0>(am, angC[2], angS[2], 0);
    gateGM< 4, 0>(am, angC[3], angS[3], 0);
    gateGM< 8, 0>(am, angC[4], angS[4], 0);
    gateGM<16, 0>(am, angC[5], angS[5], 0);
}
__device__ __forceinline__ void doG3(int tid, float2 (&am)[32], const float* angC, const float* angS) {
    gateGM< 1, 0>(am, angC[ 6], angS[ 6], 0);
    gateGM< 2, 0>(am, angC[ 7], angS[ 7], 0);
    gateGM< 4, 0>(am, angC[ 8], angS[ 8], 0);
    gateGM< 8, 0>(am, angC[ 9], angS[ 9], 0);
    gateGM<16, 0>(am, angC[10], angS[10], 0);
    u32 z1 = mmap(B3of(tid));
    gateGM< 3, parmask(PV3, 1,  7)>(am, angC[16 +  7], angS[16 +  7], (z1 >>  7) & 1u);
    gateGM< 6, parmask(PV3, 1,  8)>(am, angC[16 +  8], angS[16 +  8], (z1 >>  8) & 1u);
    gateGM<12, parmask(PV3, 1,  9)>(am, angC[16 +  9], angS[16 +  9], (z1 >>  9) & 1u);
    gateGM<24, parmask(PV3, 1, 10)>(am, angC[16 + 10], angS[16 + 10], (z1 >> 10) & 1u);
}
__device__ __forceinline__ void doG4(int tid, float2 (&am)[32], const float* angC, const float* angS) {
    u32 z1 = mmap(B4of(tid));
    gateGM< 1, parmask(PV4, 1, 2)>(am, angC[16 + 2], angS[16 + 2], (z1 >> 2) & 1u);
    gateGM< 2, parmask(PV4, 1, 3)>(am, angC[16 + 3], angS[16 + 3], (z1 >> 3) & 1u);
    gateGM< 4, parmask(PV4, 1, 4)>(am, angC[16 + 4], angS[16 + 4], (z1 >> 4) & 1u);
    gateGM< 8, parmask(PV4, 1, 5)>(am, angC[16 + 5], angS[16 + 5], (z1 >> 5) & 1u);
    gateGM<16, parmask(PV4, 1, 6)>(am, angC[16 + 6], angS[16 + 6], (z1 >> 6) & 1u);
}
__device__ __forceinline__ void doG5(int tid, float2 (&am)[32], const float* angC, const float* angS) {
    u32 z1 = mmap(B5of(tid)), z2 = mmap(z1);
    gateGM< 1, parmask(PV5, 1,  0)>(am, angC[16 +  0], angS[16 +  0], (z1 >>  0) & 1u);
    gateGM< 2, parmask(PV5, 1,  1)>(am, angC[16 +  1], angS[16 +  1], (z1 >>  1) & 1u);
    gateGM< 4, parmask(PV5, 1, 11)>(am, angC[16 + 11], angS[16 + 11], (z1 >> 11) & 1u);
    gateGM< 8, parmask(PV5, 1, 12)>(am, angC[16 + 12], angS[16 + 12], (z1 >> 12) & 1u);
    gateGM<16, parmask(PV5, 1, 13)>(am, angC[16 + 13], angS[16 + 13], (z1 >> 13) & 1u);
    gateGM<25, parmask(PV5, 2,  0)>(am, angC[32 +  0], angS[32 +  0], (z2 >>  0) & 1u);
    gateGM< 3, parmask(PV5, 2,  1)>(am, angC[32 +  1], angS[32 +  1], (z2 >>  1) & 1u);
    gateGM<12, parmask(PV5, 2, 12)>(am, angC[32 + 12], angS[32 + 12], (z2 >> 12) & 1u);
    gateGM<24, parmask(PV5, 2, 13)>(am, angC[32 + 13], angS[32 + 13], (z2 >> 13) & 1u);
}
__device__ __forceinline__ void doG6(int tid, float2 (&am)[32], const float* angC, const float* angS) {
    u32 z2 = mpow(B4of(tid), 2);
    gateGM< 1, parmask(PV6, 2, 2)>(am, angC[32 + 2], angS[32 + 2], (z2 >> 2) & 1u);
    gateGM< 2, parmask(PV6, 2, 3)>(am, angC[32 + 3], angS[32 + 3], (z2 >> 3) & 1u);
    gateGM< 4, parmask(PV6, 2, 4)>(am, angC[32 + 4], angS[32 + 4], (z2 >> 4) & 1u);
    gateGM< 8, parmask(PV6, 2, 5)>(am, angC[32 + 5], angS[32 + 5], (z2 >> 5) & 1u);
    gateGM<16, parmask(PV6, 2, 6)>(am, angC[32 + 6], angS[32 + 6], (z2 >> 6) & 1u);
}
__device__ __forceinline__ void doG7(int tid, float2 (&am)[32], const float* angC, const float* angS) {
    u32 z2 = mpow(B7of(tid), 2);
    gateGM< 1, parmask(PV7, 2,  7)>(am, angC[32 +  7], angS[32 +  7], (z2 >>  7) & 1u);
    gateGM< 2, parmask(PV7, 2,  8)>(am, angC[32 +  8], angS[32 +  8], (z2 >>  8) & 1u);
    gateGM< 4, parmask(PV7, 2,  9)>(am, angC[32 +  9], angS[32 +  9], (z2 >>  9) & 1u);
    gateGM< 8, parmask(PV7, 2, 10)>(am, angC[32 + 10], angS[32 + 10], (z2 >> 10) & 1u);
    gateGM<16, parmask(PV7, 2, 11)>(am, angC[32 + 11], angS[32 + 11], (z2 >> 11) & 1u);
}
__device__ __forceinline__ void doMeas(int tid, float2 (&am)[32], const float* lutLo,
                                       const float* lutHi, float& acc, float W0) {
    u32 wB = mpow(B7of(tid), 3);
    #pragma unroll
    for (int r = 0; r < 32; ++r) {
        u32 w = wB ^ mpow(moff(PV7, r), 3);
        float p  = fmaf(am[r].x, am[r].x, am[r].y * am[r].y);
        float wv = W0 - 2.0f * (lutLo[w & 127u] + lutHi[w >> 7]);
        acc = fmaf(wv, p, acc);
    }
}

// ---------- half-buffer LDS exchange (64KB; slot = cmpt(swzN(p), t)) ----------
// T12 t=8; T23/T34 t=12; T45/T56 t=8; T67 t=12. Bit t of swzN(p) = p_t = g(p),
// constant per round (g orthogonal to both passes' register subspaces).
__device__ __forceinline__ void doW1(int tid, float* smem, float2 (&am)[32]) {
    float4* stv = (float4*)smem;
    u32 base = cmpt(swzN((u32)tid << 2), 8);
    bool sw = (((tid >> 2) ^ (tid >> 3)) & 1) != 0;
    #pragma unroll
    for (int h = 0; h < 8; ++h)
        #pragma unroll
        for (int m = 0; m < 2; ++m) {
            u32 idx = (base ^ (((u32)h << 10) | ((u32)m << 1))) >> 1;  // cmpt(h<<11|m<<1,8)
            int r = h * 4 + m * 2;
            float2 a0 = am[r], a1 = am[r + 1];
            stv[idx] = sw ? make_float4(a1.x, a1.y, a0.x, a0.y)
                          : make_float4(a0.x, a0.y, a1.x, a1.y);
        }
}
__device__ __forceinline__ void doR2(int tid, float* smem, float2 (&am)[32]) {
    float4* stv = (float4*)smem;
    u32 base = cmpt(swzN(B2of(tid)), 8);
    #pragma unroll
    for (int h = 0; h < 16; ++h) {
        u32 idx = (base ^ swzN((u32)h << 2)) >> 1;   // offs < 64: cmpt identity
        float4 v = stv[idx];
        if (((h >> 2) ^ (h >> 3)) & 1) {
            am[h * 2 + 1] = make_float2(v.x, v.y);
            am[h * 2]     = make_float2(v.z, v.w);
        } else {
            am[h * 2]     = make_float2(v.x, v.y);
            am[h * 2 + 1] = make_float2(v.z, v.w);
        }
    }
}
__device__ __forceinline__ void doW2(int tid, float* smem, float2 (&am)[32]) {
    float4* stv = (float4*)smem;
    u32 base = cmpt(swzN(B2of(tid)), 12);
    #pragma unroll
    for (int h = 0; h < 16; ++h) {
        u32 idx = (base ^ swzN((u32)h << 2)) >> 1;
        float2 a0 = am[h * 2], a1 = am[h * 2 + 1];
        if (((h >> 2) ^ (h >> 3)) & 1) stv[idx] = make_float4(a1.x, a1.y, a0.x, a0.y);
        else                           stv[idx] = make_float4(a0.x, a0.y, a1.x, a1.y);
    }
}
__device__ __forceinline__ void doR3(int tid, float* smem, float2 (&am)[32]) {
    float2* st2 = (float2*)smem;
    u32 base = cmpt(swzN(B3of(tid)), 12);
    #pragma unroll
    for (int j = 0; j < 32; ++j) am[j] = st2[base ^ swzN((u32)j << 6)];  // offs < 2048: identity
}
__device__ __forceinline__ void doW3(int tid, float* smem, float2 (&am)[32]) {
    float2* st2 = (float2*)smem;
    u32 base = cmpt(swzN(B3of(tid)), 12);   // same slots it read (T34 == T23 mapping)
    #pragma unroll
    for (int j = 0; j < 32; ++j) st2[base ^ swzN((u32)j << 6)] = am[j];
}
__device__ __forceinline__ void doR4(int tid, float* smem, float2 (&am)[32]) {
    float2* st2 = (float2*)smem;
    u32 base = cmpt(swzN(B4of(tid)), 12);
    #pragma unroll
    for (int r = 0; r < 32; ++r) am[r] = st2[base ^ swzN(moff(PV4, r))];  // offs < 128
}
__device__ __forceinline__ void doW4(int tid, float* smem, float2 (&am)[32]) {
    float2* st2 = (float2*)smem;
    u32 base = cmpt(swzN(B4of(tid)), 8);
    #pragma unroll
    for (int r = 0; r < 32; ++r) st2[base ^ swzN(moff(PV4, r))] = am[r];
}
__device__ __forceinline__ void doR5(int tid, float* smem, float2 (&am)[32]) {
    float2* st2 = (float2*)smem;
    u32 base = cmpt(swzN(B5of(tid)), 8);
    #pragma unroll
    for (int r = 0; r < 32; ++r) am[r] = st2[base ^ cmpt(moff(PV5, r), 8)];  // swzN id on PV5
}
__device__ __forceinline__ void doW5(int tid, float* smem, float2 (&am)[32]) {
    float2* st2 = (float2*)smem;
    u32 base = cmpt(swzN(B5of(tid)), 8);    // same slots it read (T56 == T45 mapping)
    #pragma unroll
    for (int r = 0; r < 32; ++r) st2[base ^ cmpt(moff(PV5, r), 8)] = am[r];
}
__device__ __forceinline__ void doR6(int tid, float* smem, float2 (&am)[32]) {
    float2* st2 = (float2*)smem;
    u32 base = cmpt(swzN(B4of(tid)), 8);
    #pragma unroll
    for (int r = 0; r < 32; ++r) am[r] = st2[base ^ swzN(moff(PV6, r))];  // offs < 128
}
__device__ __forceinline__ void doW6(int tid, float* smem, float2 (&am)[32]) {
    float2* st2 = (float2*)smem;
    u32 base = cmpt(swzN(B4of(tid)), 12);
    #pragma unroll
    for (int r = 0; r < 32; ++r) st2[base ^ swzN(moff(PV6, r))] = am[r];
}
__device__ __forceinline__ void doR7(int tid, float* smem, float2 (&am)[32]) {
    float2* st2 = (float2*)smem;
    u32 base = cmpt(swzN(B7of(tid)), 12);
    #pragma unroll
    for (int r = 0; r < 32; ++r) am[r] = st2[base ^ swzN(moff(PV7, r))];  // offs < 4096
}

// One state per 512-thread block; 64KB half-buffer exchanged in 2 wave-uniform
// rounds per transition -> LDS/block 65.4KB -> 2 blocks/CU co-resident (TLP
// hides the barrier-aligned exposure that was ~34% of R4's runtime).
__global__ __launch_bounds__(NT, 4) void qsim_kernel(
    const float* __restrict__ sreal, const float* __restrict__ simag,
    const float* __restrict__ wts,   const float* __restrict__ hw,
    const float* __restrict__ hb,    float* __restrict__ out)
{
    extern __shared__ float smem[];
    float* angC   = smem + 16384;
    float* angS   = angC + 48;
    float* lutLo  = angS + 48;
    float* lutHi  = lutLo + 128;
    float* redbuf = lutHi + 128;

    int tid = threadIdx.x;
    int b   = blockIdx.x;
    int r6  = (tid >> 6) & 1;   // round bit for T12/T45/T56 (g = e8)
    int r7  = (tid >> 7) & 1;   // round bit for T23/T34/T67 (g = e12)

    // global load, P1 layout: float4 (h<<9)|tid covers p = (h<<11)|(tid<<2)|{0..3}
    const float4* pr = (const float4*)(sreal + (size_t)b * DIM);
    const float4* pi = (const float4*)(simag + (size_t)b * DIM);
    float2 am[32];
    #pragma unroll
    for (int h = 0; h < 8; ++h) {
        float4 r = pr[(h << 9) | tid];
        float4 i = pi[(h << 9) | tid];
        am[h * 4 + 0] = make_float2(r.x, i.x);
        am[h * 4 + 1] = make_float2(r.y, i.y);
        am[h * 4 + 2] = make_float2(r.z, i.z);
        am[h * 4 + 3] = make_float2(r.w, i.w);
    }

    // block-uniform setup: summed half-angles + head LUTs
    if (tid < 42) {
        int l = tid / 14, bb = tid % 14, q = 13 - bb;
        float a = 0.5f * (wts[l * 42 + q] + wts[l * 42 + 14 + q] + wts[l * 42 + 28 + q]);
        angC[l * 16 + bb] = cosf(a);
        angS[l * 16 + bb] = sinf(a);
    } else if (tid >= 64 && tid < 192) {
        int i = tid - 64;
        float ssum = 0.f;
        for (int bb = 0; bb < 7; ++bb) if ((i >> bb) & 1) ssum += hw[13 - bb];
        lutLo[i] = ssum;
    } else if (tid >= 192 && tid < 320) {
        int i = tid - 192;
        float ssum = 0.f;
        for (int bb = 0; bb < 7; ++bb) if ((i >> bb) & 1) ssum += hw[6 - bb];
        lutHi[i] = ssum;
    }

    __syncthreads();
    float W0  = lutLo[127] + lutHi[127];
    float acc = 0.f;

    // P1
    doG1(am, angC, angS);
    if (r6 == 0) doW1(tid, smem, am);  __syncthreads();
    if (r6 == 0) doR2(tid, smem, am);  __syncthreads();
    if (r6 == 1) doW1(tid, smem, am);  __syncthreads();
    if (r6 == 1) doR2(tid, smem, am);  __syncthreads();
    // P2
    doG2(am, angC, angS);
    if (r7 == 0) doW2(tid, smem, am);  __syncthreads();
    if (r7 == 0) doR3(tid, smem, am);  __syncthreads();
    if (r7 == 1) doW2(tid, smem, am);  __syncthreads();
    if (r7 == 1) doR3(tid, smem, am);  __syncthreads();
    // P3
    doG3(tid, am, angC, angS);
    if (r7 == 0) doW3(tid, smem, am);  __syncthreads();
    if (r7 == 0) doR4(tid, smem, am);  __syncthreads();
    if (r7 == 1) doW3(tid, smem, am);  __syncthreads();
    if (r7 == 1) doR4(tid, smem, am);  __syncthreads();
    // P4
    doG4(tid, am, angC, angS);
    if (r6 == 0) doW4(tid, smem, am);  __syncthreads();
    if (r6 == 0) doR5(tid, smem, am);  __syncthreads();
    if (r6 == 1) doW4(tid, smem, am);  __syncthreads();
    if (r6 == 1) doR5(tid, smem, am);  __syncthreads();
    // P5
    doG5(tid, am, angC, angS);
    if (r6 == 0) doW5(tid, smem, am);  __syncthreads();
    if (r6 == 0) doR6(tid, smem, am);  __syncthreads();
    if (r6 == 1) doW5(tid, smem, am);  __syncthreads();
    if (r6 == 1) doR6(tid, smem, am);  __syncthreads();
    // P6
    doG6(tid, am, angC, angS);
    if (r7 == 0) doW6(tid, smem, am);  __syncthreads();
    if (r7 == 0) doR7(tid, smem, am);  __syncthreads();
    if (r7 == 1) doW6(tid, smem, am);  __syncthreads();
    if (r7 == 1) doR7(tid, smem, am);  __syncthreads();
    // P7
    doG7(tid, am, angC, angS);
    doMeas(tid, am, lutLo, lutHi, acc, W0);

    // block reduction
    #pragma unroll
    for (int off = 32; off > 0; off >>= 1) acc += __shfl_xor(acc, off, 64);
    if ((tid & 63) == 0) redbuf[tid >> 6] = acc;
    __syncthreads();
    if (tid == 0) {
        float tot = hb[0];
        #pragma unroll
        for (int i = 0; i < 8; ++i) tot += redbuf[i];
        out[b] = tot;
    }
}

extern "C" void kernel_launch(void* const* d_in, const int* in_sizes, int n_in,
                              void* d_out, int out_size, void* d_ws, size_t ws_size,
                              hipStream_t stream)
{
    const float* sreal = (const float*)d_in[0];
    const float* simag = (const float*)d_in[1];
    const float* wts   = (const float*)d_in[2];
    const float* hw    = (const float*)d_in[3];
    const float* hb    = (const float*)d_in[4];
    float* out = (float*)d_out;

    int batch = in_sizes[0] / DIM;
    size_t smem_bytes = (16384 + 48 + 48 + 128 + 128 + 8) * sizeof(float);  // 65.4 KB -> 2 blocks/CU

    (void)hipFuncSetAttribute((const void*)qsim_kernel,
                              hipFuncAttributeMaxDynamicSharedMemorySize, (int)smem_bytes);
    qsim_kernel<<<dim3(batch), dim3(NT), smem_bytes, stream>>>(sreal, simag, wts, hw, hb, out);
}